// Round 1
// baseline (483.707 us; speedup 1.0000x reference)
//
#include <hip/hip_runtime.h>
#include <hip/hip_bf16.h>

// out = [relu(A@relu(A@F)) | A@(A@nf)], N=8192, D=E=64.
// Two skinny GEMMs (M=8192, N=128, K=8192), relu on cols<64 after each.
// Round 4: double-buffered LDS + depth-1 global prefetch in gemm_atomic.
// Old structure paid full HBM latency serially every K-iter (load -> wait ->
// cvt -> ds_write -> barrier -> ds_read -> MFMA -> barrier). New structure:
// issue tile t+1 loads, MFMA tile t from buf, cvt+ds_write t+1 into buf^1,
// ONE barrier per iter. Loads stay in flight across the compute phase.
// Dtype self-detection (bf16 OR f32 storage) retained from Round 3.

typedef unsigned short ushort_t;
typedef __attribute__((ext_vector_type(8))) short short8;   // 8 bf16 (4 VGPRs)
typedef __attribute__((ext_vector_type(4))) float f32x4;    // MFMA 16x16 acc
typedef __attribute__((ext_vector_type(4))) unsigned short us4;

#define NN 8192
#define NO 128
#define BKK 64
#define KSPAN 2048               // K per split (4 splits)
#define GITERS (KSPAN / BKK)     // 32

__global__ void detect_dtype(const ushort_t* __restrict__ A, int* __restrict__ flag) {
  __shared__ int smax, szero;
  const int t = threadIdx.x;
  if (t == 0) { smax = 0; szero = 0; }
  __syncthreads();
  int lmax = 0, lzero = 0;
  #pragma unroll
  for (int j = 0; j < 8; ++j) {
    int idx = t * 8 + j;                 // ushorts [0,2048)
    int u = (int)A[idx];
    if ((idx & 1) == 0) {                // little-endian: even = f32 low mantissa
      lmax = max(lmax, u);
      lzero += (u == 0) ? 1 : 0;
    }
  }
  atomicMax(&smax, lmax);
  atomicAdd(&szero, lzero);
  __syncthreads();
  if (t == 0) *flag = (smax > 0x3A00 || szero > 800) ? 1 : 0;
}

__global__ void zero_ws(float* __restrict__ p) {
  size_t i = ((size_t)blockIdx.x * 256 + threadIdx.x) * 4;
  *(float4*)(p + i) = make_float4(0.f, 0.f, 0.f, 0.f);
}

__device__ __forceinline__ short bf16bits(float x) {
  __hip_bfloat16 h = __float2bfloat16(x);
  return *reinterpret_cast<short*>(&h);
}

__device__ __forceinline__ short8 cvt8(float4 a, float4 b) {
  short8 r;
  r[0] = bf16bits(a.x); r[1] = bf16bits(a.y); r[2] = bf16bits(a.z); r[3] = bf16bits(a.w);
  r[4] = bf16bits(b.x); r[5] = bf16bits(b.y); r[6] = bf16bits(b.z); r[7] = bf16bits(b.w);
  return r;
}

// Bt[n][k] = concat(F,nf)^T as bf16, from either storage dtype.
__global__ void pack_bt(const ushort_t* __restrict__ F, const ushort_t* __restrict__ NF,
                        ushort_t* __restrict__ Bt, const int* __restrict__ flag) {
  int idx = blockIdx.x * 256 + threadIdx.x;   // 131072 threads
  int n = idx >> 10;                           // [0,128)
  int k0 = (idx & 1023) << 3;                  // 8 consecutive k
  ushort_t* dst = Bt + ((size_t)n << 13) + k0;
  if (*flag) {
    const float* src = (n < 64) ? ((const float*)F + n) : ((const float*)NF + (n - 64));
    #pragma unroll
    for (int j = 0; j < 8; ++j) dst[j] = (ushort_t)bf16bits(src[(size_t)(k0 + j) << 6]);
  } else {
    const ushort_t* src = (n < 64) ? (F + n) : (NF + (n - 64));
    #pragma unroll
    for (int j = 0; j < 8; ++j) dst[j] = src[(size_t)(k0 + j) << 6];
  }
}

// MFMA inner step for one staged 64(k) tile.
// mfma_f32_16x16x32_bf16 (verified layouts): A-frag lane l -> A[m=l&15][k=(l>>4)*8+j];
// B-frag: B[k=(l>>4)*8+j][n=l&15]; C/D: col=l&15, row=(l>>4)*4+reg.
__device__ __forceinline__ void compute_tile(const ushort_t* bA, const ushort_t* bB,
                                             int w, int lane, f32x4 (&acc)[4][2]) {
  #pragma unroll
  for (int s = 0; s < 2; ++s) {
    short8 b0 = *(const short8*)(bB + (4 * w + s) * 512 + lane * 8);
    short8 b1 = *(const short8*)(bB + (4 * w + 2 + s) * 512 + lane * 8);
    #pragma unroll
    for (int mt = 0; mt < 4; ++mt) {
      short8 a = *(const short8*)(bA + (2 * mt + s) * 512 + lane * 8);
      acc[mt][0] = __builtin_amdgcn_mfma_f32_16x16x32_bf16(a, b0, acc[mt][0], 0, 0, 0);
      acc[mt][1] = __builtin_amdgcn_mfma_f32_16x16x32_bf16(a, b1, acc[mt][1], 0, 0, 0);
    }
  }
}

// P[m0:m0+64][0:128] += A[m0:m0+64][kb:kb+2048] @ Bt^T slice (f32 atomics).
__global__ __launch_bounds__(256) void gemm_atomic(
    const ushort_t* __restrict__ Au, const float* __restrict__ Af,
    const ushort_t* __restrict__ Bt, float* __restrict__ P,
    const int* __restrict__ flag) {
  __shared__ __align__(16) ushort_t lsA[2][8 * 512];    // 2 x 8 KB, seg (2*mt+s)
  __shared__ __align__(16) ushort_t lsB[2][16 * 512];   // 2 x 16 KB, fragment-ordered
  const int t = threadIdx.x;
  const int w = t >> 6, lane = t & 63;
  const int mtile = blockIdx.x >> 2;
  const int split = blockIdx.x & 3;
  const size_t m0 = (size_t)mtile * 64;
  const int kb = split * KSPAN;

  const int wh = w >> 1, ws_ = w & 1;
  const int l15 = lane & 15, lq = lane >> 4;
  const size_t rowA0 = m0 + (size_t)wh * 16 + l15;
  const size_t colb = (size_t)kb + ws_ * 32 + lq * 8;
  const ushort_t* gA0b = Au + rowA0 * NN + colb;
  const ushort_t* gA1b = gA0b + (size_t)32 * NN;
  const float*    gA0f = Af + rowA0 * NN + colb;
  const float*    gA1f = gA0f + (size_t)32 * NN;
  const ushort_t* gB0 = Bt + ((size_t)wh * 16 + l15) * NN + colb;

  const f32x4 zero = {0.f, 0.f, 0.f, 0.f};
  f32x4 acc[4][2];
  #pragma unroll
  for (int mt = 0; mt < 4; ++mt) { acc[mt][0] = zero; acc[mt][1] = zero; }

  const int fl = *flag;

  if (fl) {
    // ---- f32-storage path: load f32, cvt to bf16 in regs, stage to LDS ----
    float4 a00 = *(const float4*)gA0f;
    float4 a01 = *(const float4*)(gA0f + 4);
    float4 a10 = *(const float4*)gA1f;
    float4 a11 = *(const float4*)(gA1f + 4);
    short8 rb0 = *(const short8*)gB0;
    short8 rb1 = *(const short8*)(gB0 + (size_t)32 * NN);
    short8 rb2 = *(const short8*)(gB0 + (size_t)64 * NN);
    short8 rb3 = *(const short8*)(gB0 + (size_t)96 * NN);
    gA0f += BKK; gA1f += BKK; gB0 += BKK;
    *(short8*)(lsA[0] + t * 8) = cvt8(a00, a01);
    *(short8*)(lsA[0] + t * 8 + 2048) = cvt8(a10, a11);
    *(short8*)(lsB[0] + t * 8) = rb0;
    *(short8*)(lsB[0] + t * 8 + 2048) = rb1;
    *(short8*)(lsB[0] + t * 8 + 4096) = rb2;
    *(short8*)(lsB[0] + t * 8 + 6144) = rb3;
    __syncthreads();
    int buf = 0;
    for (int it = 0; it < GITERS - 1; ++it) {
      // issue next tile's global loads (in flight across the MFMAs below)
      a00 = *(const float4*)gA0f;
      a01 = *(const float4*)(gA0f + 4);
      a10 = *(const float4*)gA1f;
      a11 = *(const float4*)(gA1f + 4);
      rb0 = *(const short8*)gB0;
      rb1 = *(const short8*)(gB0 + (size_t)32 * NN);
      rb2 = *(const short8*)(gB0 + (size_t)64 * NN);
      rb3 = *(const short8*)(gB0 + (size_t)96 * NN);
      gA0f += BKK; gA1f += BKK; gB0 += BKK;
      // compute current tile from buf (no dependence on the loads above)
      compute_tile(lsA[buf], lsB[buf], w, lane, acc);
      // vmcnt wait lands here, after the MFMAs; stage into the other buffer
      const int nb = buf ^ 1;
      *(short8*)(lsA[nb] + t * 8) = cvt8(a00, a01);
      *(short8*)(lsA[nb] + t * 8 + 2048) = cvt8(a10, a11);
      *(short8*)(lsB[nb] + t * 8) = rb0;
      *(short8*)(lsB[nb] + t * 8 + 2048) = rb1;
      *(short8*)(lsB[nb] + t * 8 + 4096) = rb2;
      *(short8*)(lsB[nb] + t * 8 + 6144) = rb3;
      __syncthreads();
      buf = nb;
    }
    compute_tile(lsA[buf], lsB[buf], w, lane, acc);
  } else {
    // ---- bf16-storage path ----
    short8 ra0 = *(const short8*)gA0b;
    short8 ra1 = *(const short8*)gA1b;
    short8 rb0 = *(const short8*)gB0;
    short8 rb1 = *(const short8*)(gB0 + (size_t)32 * NN);
    short8 rb2 = *(const short8*)(gB0 + (size_t)64 * NN);
    short8 rb3 = *(const short8*)(gB0 + (size_t)96 * NN);
    gA0b += BKK; gA1b += BKK; gB0 += BKK;
    *(short8*)(lsA[0] + t * 8) = ra0;
    *(short8*)(lsA[0] + t * 8 + 2048) = ra1;
    *(short8*)(lsB[0] + t * 8) = rb0;
    *(short8*)(lsB[0] + t * 8 + 2048) = rb1;
    *(short8*)(lsB[0] + t * 8 + 4096) = rb2;
    *(short8*)(lsB[0] + t * 8 + 6144) = rb3;
    __syncthreads();
    int buf = 0;
    for (int it = 0; it < GITERS - 1; ++it) {
      ra0 = *(const short8*)gA0b;
      ra1 = *(const short8*)gA1b;
      rb0 = *(const short8*)gB0;
      rb1 = *(const short8*)(gB0 + (size_t)32 * NN);
      rb2 = *(const short8*)(gB0 + (size_t)64 * NN);
      rb3 = *(const short8*)(gB0 + (size_t)96 * NN);
      gA0b += BKK; gA1b += BKK; gB0 += BKK;
      compute_tile(lsA[buf], lsB[buf], w, lane, acc);
      const int nb = buf ^ 1;
      *(short8*)(lsA[nb] + t * 8) = ra0;
      *(short8*)(lsA[nb] + t * 8 + 2048) = ra1;
      *(short8*)(lsB[nb] + t * 8) = rb0;
      *(short8*)(lsB[nb] + t * 8 + 2048) = rb1;
      *(short8*)(lsB[nb] + t * 8 + 4096) = rb2;
      *(short8*)(lsB[nb] + t * 8 + 6144) = rb3;
      __syncthreads();
      buf = nb;
    }
    compute_tile(lsA[buf], lsB[buf], w, lane, acc);
  }

  const int cn0 = 32 * w + l15;
  const int rb = lq * 4;
  #pragma unroll
  for (int mt = 0; mt < 4; ++mt) {
    float* dst = P + (m0 + mt * 16 + rb) * NO;
    #pragma unroll
    for (int reg = 0; reg < 4; ++reg) {
      unsafeAtomicAdd(&dst[(size_t)reg * NO + cn0], acc[mt][0][reg]);
      unsafeAtomicAdd(&dst[(size_t)reg * NO + cn0 + 16], acc[mt][1][reg]);
    }
  }
}

// P -> bf16, relu cols<64, TRANSPOSED (Bt layout) into ws for GEMM2.
__global__ void epi_t(const float* __restrict__ P, ushort_t* __restrict__ Ct) {
  __shared__ ushort_t lt[128 * 65];
  const size_t base = (size_t)blockIdx.x * (64 * NO);
  const int t = threadIdx.x;
  for (int i = 0; i < 32; ++i) {
    int e = i * 256 + t;
    int n = e & 127, m = e >> 7;
    float v = P[base + e];
    if (n < 64) v = fmaxf(v, 0.f);
    lt[n * 65 + m] = (ushort_t)bf16bits(v);
  }
  __syncthreads();
  const int n = t >> 1, h = t & 1;
  const size_t m0 = (size_t)blockIdx.x * 64;
  ushort_t* dst = Ct + (size_t)n * NN + m0 + h * 32;
  #pragma unroll
  for (int j = 0; j < 32; ++j) dst[j] = lt[n * 65 + h * 32 + j];
}

// P -> relu cols<64 -> output in detected dtype.
__global__ void epi_out(const float* __restrict__ P, ushort_t* __restrict__ outb,
                        float* __restrict__ outf, const int* __restrict__ flag) {
  int idx = blockIdx.x * 256 + threadIdx.x;  // 262144 threads
  size_t e = (size_t)idx * 4;
  float4 v = *(const float4*)(P + e);
  float s[4] = {v.x, v.y, v.z, v.w};
  int n0 = (int)(e & 127);
  #pragma unroll
  for (int j = 0; j < 4; ++j) if (n0 + j < 64) s[j] = fmaxf(s[j], 0.f);
  if (*flag) {
    *(float4*)(outf + e) = make_float4(s[0], s[1], s[2], s[3]);
  } else {
    us4 r;
    #pragma unroll
    for (int j = 0; j < 4; ++j) r[j] = (ushort_t)bf16bits(s[j]);
    *(us4*)(outb + e) = r;
  }
}

extern "C" void kernel_launch(void* const* d_in, const int* in_sizes, int n_in,
                              void* d_out, int out_size, void* d_ws, size_t ws_size,
                              hipStream_t stream) {
  const ushort_t* A  = (const ushort_t*)d_in[0];   // [8192][8192]
  const ushort_t* F  = (const ushort_t*)d_in[1];   // [8192][64]
  const ushort_t* NF = (const ushort_t*)d_in[2];   // [8192][64]

  char* ws = (char*)d_ws;
  ushort_t* Bt = (ushort_t*)(ws);                  // 2 MB  [128][8192] bf16
  ushort_t* Ct = (ushort_t*)(ws + (2u << 20));     // 2 MB  [128][8192] bf16
  float*    P1 = (float*)(ws + (4u << 20));        // 4 MB  f32 [8192][128]
  float*    P2 = (float*)(ws + (8u << 20));        // 4 MB
  int*    flag = (int*)(ws + (12u << 20));         // 4 B   (total ws: 12 MB + 4)

  detect_dtype<<<1, 256, 0, stream>>>(A, flag);
  zero_ws<<<2048, 256, 0, stream>>>(P1);           // zeros P1+P2 (8 MB, contiguous)
  pack_bt<<<512, 256, 0, stream>>>(F, NF, Bt, flag);
  gemm_atomic<<<512, 256, 0, stream>>>(A, (const float*)A, Bt, P1, flag);  // layer 1
  epi_t<<<128, 256, 0, stream>>>(P1, Ct);
  gemm_atomic<<<512, 256, 0, stream>>>(A, (const float*)A, Ct, P2, flag);  // layer 2
  epi_out<<<1024, 256, 0, stream>>>(P2, (ushort_t*)d_out, (float*)d_out, flag);
}